// Round 4
// baseline (33.962 us; speedup 1.0000x reference)
//
#include <hip/hip_runtime.h>

#define RR 256
#define LAMBDA_TV 1e-5f
#define TV_EPS 1e-9f

typedef float f32x4 __attribute__((ext_vector_type(4)));

// K1: fused (a) per-cell gather + compute -> compact (idx,val) pair list in
// d_ws, (b) zero the 33.5 MB output with non-temporal stores. The two parts
// touch disjoint buffers, so no inter-block ordering is needed; the random
// density gathers (3-deep dependent chain, ~335K random 64B lines) overlap
// with the streaming zero writes instead of serializing behind them.
__global__ void tv_compute_zero_kernel(const float* __restrict__ density,
                                       const int* __restrict__ links,
                                       const int* __restrict__ cells,
                                       f32x4* __restrict__ out4, int n4,
                                       int4* __restrict__ pairs2, // 2*ncells int4 = 4*ncells (idx,val)
                                       int ncells) {
    int tid = blockIdx.x * blockDim.x + threadIdx.x;
    int nthreads = gridDim.x * blockDim.x;

    if (tid < ncells) {
        int cell = cells[tid];
        int z = cell & (RR - 1);
        int y = (cell >> 8) & (RR - 1);
        int x = cell >> 16;

        bool in100 = (x + 1 < RR);
        bool in010 = (y + 1 < RR);
        bool in001 = (z + 1 < RR);

        int l000 = links[cell];
        int l100 = in100 ? links[cell + RR * RR] : -1;
        int l010 = in010 ? links[cell + RR] : -1;
        int l001 = in001 ? links[cell + 1] : -1;

        float v000 = (l000 >= 0) ? density[l000] : 0.0f;
        float v100 = in100 ? ((l100 >= 0) ? density[l100] : 0.0f) : v000;
        float v010 = in010 ? ((l010 >= 0) ? density[l010] : 0.0f) : v000;
        float v001 = in001 ? ((l001 >= 0) ? density[l001] : 0.0f) : v000;

        const float s = RR * 0.5f;
        float dx = (v100 - v000) * s;
        float dy = (v010 - v000) * s;
        float dz = (v001 - v000) * s;

        float idelta = LAMBDA_TV * rsqrtf(TV_EPS + dx * dx + dy * dy + dz * dz);

        int4 p01, p23;
        p01.x = l000; p01.y = __float_as_int(-(dx + dy + dz) * idelta);
        p01.z = l100; p01.w = __float_as_int(dx * idelta);
        p23.x = l010; p23.y = __float_as_int(dy * idelta);
        p23.z = l001; p23.w = __float_as_int(dz * idelta);
        pairs2[2 * tid]     = p01;
        pairs2[2 * tid + 1] = p23;
    }

    // Zero the output (grid covers it in 4 strides of f32x4). Non-temporal:
    // don't let 33.5 MB of zeros evict the density gather lines from L2.
    f32x4 zz = {0.0f, 0.0f, 0.0f, 0.0f};
    for (int k = tid; k < n4; k += nthreads) {
        __builtin_nontemporal_store(zz, &out4[k]);
    }
}

// K2: stream the compact pair list (coalesced 8B/lane) and scatter with
// device-scope atomics. Only this small pass sits after the zero barrier.
__global__ void tv_apply_kernel(const int2* __restrict__ pairs,
                                float* __restrict__ grad, int npairs) {
    int j = blockIdx.x * blockDim.x + threadIdx.x;
    if (j >= npairs) return;
    int2 p = pairs[j];
    if (p.x >= 0) atomicAdd(&grad[p.x], __int_as_float(p.y));
}

extern "C" void kernel_launch(void* const* d_in, const int* in_sizes, int n_in,
                              void* d_out, int out_size, void* d_ws, size_t ws_size,
                              hipStream_t stream) {
    const float* density = (const float*)d_in[0];   // (N, 1) f32
    const int* links     = (const int*)d_in[1];     // (R, R, R) i32
    const int* cells     = (const int*)d_in[2];     // (sparse_num,) i32
    float* out           = (float*)d_out;           // (N, 1) f32

    int num_cells = in_sizes[2];
    int n4 = out_size / 4;               // 2097152 f32x4s = 33.5 MB

    int4* pairs2 = (int4*)d_ws;          // 2*ncells int4 (fully overwritten each call)

    // K1: 2048 blocks x 256 = 524288 threads; covers ncells (<= 524288) and
    // zeroes n4 in exactly 4 strides.
    tv_compute_zero_kernel<<<2048, 256, 0, stream>>>(
        density, links, cells, (f32x4*)out, n4, pairs2, num_cells);

    int npairs = 4 * num_cells;
    int blocks2 = (npairs + 255) / 256;
    tv_apply_kernel<<<blocks2, 256, 0, stream>>>((const int2*)pairs2, out, npairs);
}